// Round 4
// baseline (283.471 us; speedup 1.0000x reference)
//
#include <hip/hip_runtime.h>
#include <math.h>

#define NS 512
#define NF 40
#define ROWS_OUT 513
#define DTC (1.0f / 512.0f)
#define PLANE 520   // floats per component plane (512 + 8 pad)

// ws layout (floats):
//   [0..511]      w[m]            (device-computed, fp64)
//   [512..1023]   cumw2[t]        (device-computed, fp64 prefix)
//   [1024..1343]  per-forward constants, 8 per n:
//       0..2: cC = vol_scale*L[n]   3: q = nu*rho/vol_scale
//       4: cA3 = nu*sqrt(1-rho^2)   5: ca = 0.5*nu^2*DT
//       6: cm0 = mu0*DT             7: F0[n]

__global__ __launch_bounds__(64) void const_kernel(
    const float* __restrict__ F0, const float* __restrict__ alphas,
    const float* __restrict__ rhos, const float* __restrict__ nus,
    const float* __restrict__ tau, const float* __restrict__ L,
    const float* __restrict__ Lam, float* __restrict__ ws)
{
    __shared__ double wd[NS];
    __shared__ float omega0[NF];
    __shared__ float vs_s[NF];
    int n = threadIdx.x;

    // Fractional-kernel weights in fp64 on device (no inputs needed).
    {
        const double g06 = 1.4891922488128171;      // Gamma(0.6)
        const double dta = pow(512.0, 0.4);         // DT^ALPHA
        #pragma unroll
        for (int k = 0; k < 8; ++k) {
            int m = n * 8 + k;
            double wv = (pow((double)m + 1.0, 0.6) - pow((double)m, 0.6)) * (1.0 / 0.6) * dta / g06;
            wd[m] = wv;
            ws[m] = (float)wv;
        }
    }
    if (n < NF) {
        float f0 = F0[n];
        float vs = alphas[n] * sqrtf(fabsf(f0 + 0.02f));
        vs_s[n] = vs;
        omega0[n] = tau[n] * vs / (1.0f + tau[n] * f0);
    }
    __syncthreads();
    if (n == 0) {
        // serial fp64 prefix: same accumulation order as the original host loop
        double acc = 0.0;
        for (int m = 0; m < NS; ++m) { acc += wd[m] * wd[m]; ws[NS + m] = (float)acc; }
    }
    if (n < NF) {
        float s = 0.0f;
        for (int j = 0; j < NF; ++j) s += Lam[n * NF + j] * omega0[j];
        float vs = vs_s[n];
        float mu0 = -vs * s;
        float rho = rhos[n], nu = nus[n];
        float* c = ws + 1024 + n * 8;
        c[0] = vs * L[n * 3 + 0];
        c[1] = vs * L[n * 3 + 1];
        c[2] = vs * L[n * 3 + 2];
        c[3] = nu * rho / fmaxf(vs, 1e-30f);
        c[4] = nu * sqrtf(fmaxf(1.0f - rho * rho, 0.0f));
        c[5] = 0.5f * nu * nu * DTC;
        c[6] = mu0 * DTC;
        c[7] = F0[n];
    }
}

// ---- wave64 inclusive scan via DPP (pure VALU) ----
template<int CTRL, int RM>
__device__ __forceinline__ float dpp_add(float v) {
    int t = __builtin_amdgcn_update_dpp(0, __float_as_int(v), CTRL, RM, 0xf, true);
    return v + __int_as_float(t);
}
__device__ __forceinline__ float wave_iscan(float v) {
    v = dpp_add<0x111, 0xf>(v);   // row_shr:1
    v = dpp_add<0x112, 0xf>(v);   // row_shr:2
    v = dpp_add<0x114, 0xf>(v);   // row_shr:4
    v = dpp_add<0x118, 0xf>(v);   // row_shr:8
    v = dpp_add<0x142, 0xa>(v);   // row_bcast:15 -> rows 1,3
    v = dpp_add<0x143, 0xc>(v);   // row_bcast:31 -> rows 2,3
    return v;
}

__device__ __forceinline__ void fma4(float4& acc, float c, const float4& v) {
    acc.x = fmaf(c, v.x, acc.x);
    acc.y = fmaf(c, v.y, acc.y);
    acc.z = fmaf(c, v.z, acc.z);
    acc.w = fmaf(c, v.w, acc.w);
}

// 256 threads = 4 waves; 2 paths per block.
__global__ __launch_bounds__(256, 4) void path_kernel(
    const float* __restrict__ dz, const float* __restrict__ ws,
    float* __restrict__ out)
{
    __shared__ float planes[2 * 4 * PLANE]; // 16640 B: fbm4, component-major
    __shared__ float wp[768];               // 3072 B: wp[j] = (j<256 ? 0 : w[j-256])
    __shared__ float cw2[NS];               // 2048 B
    __shared__ float chunk[64 * 41];        // 10496 B  (total 32256 B)

    int tid = threadIdx.x;
    int lane = tid & 63;
    int wv = __builtin_amdgcn_readfirstlane(tid >> 6);
    int pA = blockIdx.x * 2, pB = pA + 1;
    const float4* dzgA = (const float4*)dz + (size_t)pA * NS;
    const float4* dzgB = (const float4*)dz + (size_t)pB * NS;

    for (int i = tid; i < 768; i += 256) wp[i] = (i < 256) ? 0.0f : ws[i - 256];
    for (int i = tid; i < NS; i += 256) cw2[i] = ws[NS + i];
    __syncthreads();

    // ---- Phase B: fbm4[t] = sum_s w[t-s]*dz[s]; all 4 waves.
    // Role permuted by blockIdx so each SIMD hosts a lo/hi mix across its 4
    // resident blocks (wave i of every block lands on SIMD i%4; identical role
    // maps would put all 128-iter waves on SIMDs 1/3 and all 64-iter on 0/2).
    {
        int role = (wv + (blockIdx.x & 3)) & 3;
        int path = role >> 1;
        int half = role & 1;
        int i = half * 64 + lane;           // quad index: t = 4i..4i+3
        int gmax = half ? 128 : 64;         // triangular skip at wave granularity
        const float4* dzg = path ? dzgB : dzgA;
        float* pf = planes + path * 4 * PLANE;
        const float4* wp4 = (const float4*)wp;
        float4 a0 = make_float4(0.f, 0.f, 0.f, 0.f);
        float4 a1 = a0, a2 = a0, a3 = a0;
        // weight-window register rotation: hi(g+1) == lo(g), so only one
        // ds_read_b128 per iteration (halves LDS traffic + bank conflicts).
        float4 hi = wp4[64 + i];
        #pragma unroll 2
        for (int g = 0; g < gmax; ++g) {
            float4 d0 = dzg[4 * g + 0];     // wave-uniform address -> SGPRs
            float4 d1 = dzg[4 * g + 1];
            float4 d2 = dzg[4 * g + 2];
            float4 d3 = dzg[4 * g + 3];
            float4 lo = wp4[63 + i - g];    // w[t0-s0-4 .. t0-s0-1]
            fma4(a0, hi.x, d0); fma4(a1, hi.y, d0); fma4(a2, hi.z, d0); fma4(a3, hi.w, d0);
            fma4(a0, lo.w, d1); fma4(a1, hi.x, d1); fma4(a2, hi.y, d1); fma4(a3, hi.z, d1);
            fma4(a0, lo.z, d2); fma4(a1, lo.w, d2); fma4(a2, hi.x, d2); fma4(a3, hi.y, d2);
            fma4(a0, lo.y, d3); fma4(a1, lo.z, d3); fma4(a2, lo.w, d3); fma4(a3, hi.x, d3);
            hi = lo;
        }
        // component-major planes: lane-stride-16B b128 writes, conflict-free
        ((float4*)(pf + 0 * PLANE))[i] = make_float4(a0.x, a1.x, a2.x, a3.x);
        ((float4*)(pf + 1 * PLANE))[i] = make_float4(a0.y, a1.y, a2.y, a3.y);
        ((float4*)(pf + 2 * PLANE))[i] = make_float4(a0.z, a1.z, a2.z, a3.z);
        ((float4*)(pf + 3 * PLANE))[i] = make_float4(a0.w, a1.w, a2.w, a3.w);
    }

    float carryA[10], carryB[10];
    #pragma unroll
    for (int j = 0; j < 10; ++j) { carryA[j] = 0.0f; carryB[j] = 0.0f; }

    float* outA = out + (size_t)pA * (ROWS_OUT * NF);
    float* outB = out + (size_t)pB * (ROWS_OUT * NF);
    if (tid < NF) outA[tid] = ws[1024 + tid * 8 + 7];               // row 0 = F0
    if (tid >= 64 && tid < 64 + NF) outB[tid - 64] = ws[1024 + (tid - 64) * 8 + 7];

    __syncthreads();

    // ---- Phase C/D: per chunk of 64 t (lane = t): dF, DPP scan, transpose, store.
    for (int cix = 0; cix < 8; ++cix) {
        int t = cix * 64 + lane;
        float cw = cw2[t];
        #pragma unroll
        for (int path = 0; path < 2; ++path) {
            const float* pf = planes + path * 4 * PLANE;
            float fx = pf[t], fy = pf[PLANE + t], fz = pf[2 * PLANE + t], fw = pf[3 * PLANE + t];
            float4 d = path ? dzgB[t] : dzgA[t];
            float* carry = path ? carryB : carryA;
            #pragma unroll
            for (int j = 0; j < 10; ++j) {
                int n = wv * 10 + j;                 // wave-uniform -> scalar loads
                const float* c = ws + 1024 + n * 8;
                float cC0 = c[0], cC1 = c[1], cC2 = c[2], q = c[3];
                float cA3 = c[4], ca = c[5], cm0 = c[6], f0 = c[7];
                float dotf = fx * cC0 + fy * cC1 + fz * cC2;
                float arg = fmaf(q, dotf, fmaf(cA3, fw, -ca * cw));
                float uv = __expf(arg);
                float dotc = d.x * cC0 + d.y * cC1 + d.z * cC2;
                float dF = uv * fmaf(cm0, uv, dotc);
                float v = wave_iscan(dF) + carry[j];
                carry[j] = __int_as_float(__builtin_amdgcn_readlane(__float_as_int(v), 63));
                chunk[lane * 41 + n] = v + f0;
            }
            __syncthreads();
            float* o = (path ? outB : outA) + NF + cix * (64 * NF);
            #pragma unroll
            for (int k = 0; k < 10; ++k) {
                int f = tid + k * 256;               // 2560 = 64 rows x 40 fwd, contiguous
                __builtin_nontemporal_store(chunk[f + f / 40], o + f);
            }
            __syncthreads();
        }
    }
}

extern "C" void kernel_launch(void* const* d_in, const int* in_sizes, int n_in,
                              void* d_out, int out_size, void* d_ws, size_t ws_size,
                              hipStream_t stream) {
    const float* dz   = (const float*)d_in[0];
    const float* F0   = (const float*)d_in[1];
    const float* alph = (const float*)d_in[2];
    const float* rhos = (const float*)d_in[3];
    const float* nus  = (const float*)d_in[4];
    const float* tau  = (const float*)d_in[5];
    const float* L    = (const float*)d_in[6];
    const float* Lam  = (const float*)d_in[7];
    float* ws = (float*)d_ws;
    float* out = (float*)d_out;

    int n_paths = in_sizes[0] / (NS * 4);

    const_kernel<<<1, 64, 0, stream>>>(F0, alph, rhos, nus, tau, L, Lam, ws);
    path_kernel<<<n_paths / 2, 256, 0, stream>>>(dz, ws, out);
}

// Round 5
// 273.876 us; speedup vs baseline: 1.0350x; 1.0350x over previous
//
#include <hip/hip_runtime.h>
#include <math.h>

#define NS 512
#define NF 40
#define ROWS_OUT 513
#define DTC (1.0f / 512.0f)
#define PLANE 520   // floats per component plane (512 + 8 pad)

// ws layout (floats):
//   [0..511]      w[m]            (device-computed, fp64)
//   [512..1023]   cumw2[t]        (device-computed, fp64 prefix)
//   [1024..1343]  per-forward constants, 8 per n:
//       0..2: cC = vol_scale*L[n]   3: q = nu*rho/vol_scale
//       4: cA3 = nu*sqrt(1-rho^2)   5: ca = 0.5*nu^2*DT
//       6: cm0 = mu0*DT             7: F0[n]

__global__ __launch_bounds__(64) void const_kernel(
    const float* __restrict__ F0, const float* __restrict__ alphas,
    const float* __restrict__ rhos, const float* __restrict__ nus,
    const float* __restrict__ tau, const float* __restrict__ L,
    const float* __restrict__ Lam, float* __restrict__ ws)
{
    __shared__ double wd[NS];
    __shared__ float omega0[NF];
    __shared__ float vs_s[NF];
    int n = threadIdx.x;

    // Fractional-kernel weights in fp64 on device (no inputs needed).
    {
        const double g06 = 1.4891922488128171;      // Gamma(0.6)
        const double dta = pow(512.0, 0.4);         // DT^ALPHA
        #pragma unroll
        for (int k = 0; k < 8; ++k) {
            int m = n * 8 + k;
            double wv = (pow((double)m + 1.0, 0.6) - pow((double)m, 0.6)) * (1.0 / 0.6) * dta / g06;
            wd[m] = wv;
            ws[m] = (float)wv;
        }
    }
    if (n < NF) {
        float f0 = F0[n];
        float vs = alphas[n] * sqrtf(fabsf(f0 + 0.02f));
        vs_s[n] = vs;
        omega0[n] = tau[n] * vs / (1.0f + tau[n] * f0);
    }
    __syncthreads();
    if (n == 0) {
        // serial fp64 prefix: same accumulation order as the original host loop
        double acc = 0.0;
        for (int m = 0; m < NS; ++m) { acc += wd[m] * wd[m]; ws[NS + m] = (float)acc; }
    }
    if (n < NF) {
        float s = 0.0f;
        for (int j = 0; j < NF; ++j) s += Lam[n * NF + j] * omega0[j];
        float vs = vs_s[n];
        float mu0 = -vs * s;
        float rho = rhos[n], nu = nus[n];
        float* c = ws + 1024 + n * 8;
        c[0] = vs * L[n * 3 + 0];
        c[1] = vs * L[n * 3 + 1];
        c[2] = vs * L[n * 3 + 2];
        c[3] = nu * rho / fmaxf(vs, 1e-30f);
        c[4] = nu * sqrtf(fmaxf(1.0f - rho * rho, 0.0f));
        c[5] = 0.5f * nu * nu * DTC;
        c[6] = mu0 * DTC;
        c[7] = F0[n];
    }
}

// ---- wave64 inclusive scan via DPP (pure VALU) ----
template<int CTRL, int RM>
__device__ __forceinline__ float dpp_add(float v) {
    int t = __builtin_amdgcn_update_dpp(0, __float_as_int(v), CTRL, RM, 0xf, true);
    return v + __int_as_float(t);
}
__device__ __forceinline__ float wave_iscan(float v) {
    v = dpp_add<0x111, 0xf>(v);   // row_shr:1
    v = dpp_add<0x112, 0xf>(v);   // row_shr:2
    v = dpp_add<0x114, 0xf>(v);   // row_shr:4
    v = dpp_add<0x118, 0xf>(v);   // row_shr:8
    v = dpp_add<0x142, 0xa>(v);   // row_bcast:15 -> rows 1,3
    v = dpp_add<0x143, 0xc>(v);   // row_bcast:31 -> rows 2,3
    return v;
}

// ---- packed fp32 FMA (v_pk_fma_f32): 2 FMA/lane/instr ----
typedef float v2f __attribute__((ext_vector_type(2)));
__device__ __forceinline__ void pkfma(v2f& acc, float c, v2f v) {
    acc = __builtin_elementwise_fma((v2f){c, c}, v, acc);
}

// 256 threads = 4 waves; 2 paths per block.
__global__ __launch_bounds__(256, 4) void path_kernel(
    const float* __restrict__ dz, const float* __restrict__ ws,
    float* __restrict__ out)
{
    __shared__ float planes[2 * 4 * PLANE]; // 16640 B: fbm4, component-major
    __shared__ float wp[768];               // 3072 B: wp[j] = (j<256 ? 0 : w[j-256])
    __shared__ float cw2[NS];               // 2048 B
    __shared__ float chunk[64 * 41];        // 10496 B  (total 32256 B)

    int tid = threadIdx.x;
    int lane = tid & 63;
    int wv = __builtin_amdgcn_readfirstlane(tid >> 6);
    int pA = blockIdx.x * 2, pB = pA + 1;
    const float4* dzgA = (const float4*)dz + (size_t)pA * NS;
    const float4* dzgB = (const float4*)dz + (size_t)pB * NS;

    for (int i = tid; i < 768; i += 256) wp[i] = (i < 256) ? 0.0f : ws[i - 256];
    for (int i = tid; i < NS; i += 256) cw2[i] = ws[NS + i];
    __syncthreads();

    // ---- Phase B: fbm4[t] = sum_s w[t-s]*dz[s]; all 4 waves (R0 structure,
    // packed v_pk_fma_f32: 32 pk-FMAs per g-iter instead of 64 scalar).
    {
        int path = wv >> 1;
        int half = wv & 1;
        int i = half * 64 + lane;           // quad index: t = 4i..4i+3
        int gmax = half ? 128 : 64;         // triangular skip at wave granularity
        const float4* dzg = path ? dzgB : dzgA;
        float* pf = planes + path * 4 * PLANE;
        const float4* wp4 = (const float4*)wp;
        v2f z2 = (v2f){0.f, 0.f};
        v2f a0l = z2, a0h = z2, a1l = z2, a1h = z2;
        v2f a2l = z2, a2h = z2, a3l = z2, a3h = z2;
        #pragma unroll 2
        for (int g = 0; g < gmax; ++g) {
            float4 d0 = dzg[4 * g + 0];     // wave-uniform address
            float4 d1 = dzg[4 * g + 1];
            float4 d2 = dzg[4 * g + 2];
            float4 d3 = dzg[4 * g + 3];
            v2f d0l = (v2f){d0.x, d0.y}, d0h = (v2f){d0.z, d0.w};
            v2f d1l = (v2f){d1.x, d1.y}, d1h = (v2f){d1.z, d1.w};
            v2f d2l = (v2f){d2.x, d2.y}, d2h = (v2f){d2.z, d2.w};
            v2f d3l = (v2f){d3.x, d3.y}, d3h = (v2f){d3.z, d3.w};
            float4 lo = wp4[63 + i - g];    // w[t0-s0-4 .. t0-s0-1]
            float4 hi = wp4[64 + i - g];    // w[t0-s0 .. t0-s0+3]
            pkfma(a0l, hi.x, d0l); pkfma(a0h, hi.x, d0h);
            pkfma(a1l, hi.y, d0l); pkfma(a1h, hi.y, d0h);
            pkfma(a2l, hi.z, d0l); pkfma(a2h, hi.z, d0h);
            pkfma(a3l, hi.w, d0l); pkfma(a3h, hi.w, d0h);
            pkfma(a0l, lo.w, d1l); pkfma(a0h, lo.w, d1h);
            pkfma(a1l, hi.x, d1l); pkfma(a1h, hi.x, d1h);
            pkfma(a2l, hi.y, d1l); pkfma(a2h, hi.y, d1h);
            pkfma(a3l, hi.z, d1l); pkfma(a3h, hi.z, d1h);
            pkfma(a0l, lo.z, d2l); pkfma(a0h, lo.z, d2h);
            pkfma(a1l, lo.w, d2l); pkfma(a1h, lo.w, d2h);
            pkfma(a2l, hi.x, d2l); pkfma(a2h, hi.x, d2h);
            pkfma(a3l, hi.y, d2l); pkfma(a3h, hi.y, d2h);
            pkfma(a0l, lo.y, d3l); pkfma(a0h, lo.y, d3h);
            pkfma(a1l, lo.z, d3l); pkfma(a1h, lo.z, d3h);
            pkfma(a2l, lo.w, d3l); pkfma(a2h, lo.w, d3h);
            pkfma(a3l, hi.x, d3l); pkfma(a3h, hi.x, d3h);
        }
        // component-major planes: lane-stride-16B b128 writes
        ((float4*)(pf + 0 * PLANE))[i] = make_float4(a0l.x, a1l.x, a2l.x, a3l.x);
        ((float4*)(pf + 1 * PLANE))[i] = make_float4(a0l.y, a1l.y, a2l.y, a3l.y);
        ((float4*)(pf + 2 * PLANE))[i] = make_float4(a0h.x, a1h.x, a2h.x, a3h.x);
        ((float4*)(pf + 3 * PLANE))[i] = make_float4(a0h.y, a1h.y, a2h.y, a3h.y);
    }

    float carryA[10], carryB[10];
    #pragma unroll
    for (int j = 0; j < 10; ++j) { carryA[j] = 0.0f; carryB[j] = 0.0f; }

    float* outA = out + (size_t)pA * (ROWS_OUT * NF);
    float* outB = out + (size_t)pB * (ROWS_OUT * NF);
    if (tid < NF) outA[tid] = ws[1024 + tid * 8 + 7];               // row 0 = F0
    if (tid >= 64 && tid < 64 + NF) outB[tid - 64] = ws[1024 + (tid - 64) * 8 + 7];

    __syncthreads();

    // ---- Phase C/D: per chunk of 64 t (lane = t): dF, DPP scan, transpose, store.
    for (int cix = 0; cix < 8; ++cix) {
        int t = cix * 64 + lane;
        float cw = cw2[t];
        #pragma unroll
        for (int path = 0; path < 2; ++path) {
            const float* pf = planes + path * 4 * PLANE;
            float fx = pf[t], fy = pf[PLANE + t], fz = pf[2 * PLANE + t], fw = pf[3 * PLANE + t];
            float4 d = path ? dzgB[t] : dzgA[t];
            float* carry = path ? carryB : carryA;
            #pragma unroll
            for (int j = 0; j < 10; ++j) {
                int n = wv * 10 + j;                 // wave-uniform -> scalar loads
                const float* c = ws + 1024 + n * 8;
                float cC0 = c[0], cC1 = c[1], cC2 = c[2], q = c[3];
                float cA3 = c[4], ca = c[5], cm0 = c[6], f0 = c[7];
                float dotf = fx * cC0 + fy * cC1 + fz * cC2;
                float arg = fmaf(q, dotf, fmaf(cA3, fw, -ca * cw));
                float uv = __expf(arg);
                float dotc = d.x * cC0 + d.y * cC1 + d.z * cC2;
                float dF = uv * fmaf(cm0, uv, dotc);
                float v = wave_iscan(dF) + carry[j];
                carry[j] = __int_as_float(__builtin_amdgcn_readlane(__float_as_int(v), 63));
                chunk[lane * 41 + n] = v + f0;
            }
            __syncthreads();
            float* o = (path ? outB : outA) + NF + cix * (64 * NF);
            #pragma unroll
            for (int k = 0; k < 10; ++k) {
                int f = tid + k * 256;               // 2560 = 64 rows x 40 fwd, contiguous
                __builtin_nontemporal_store(chunk[f + f / 40], o + f);
            }
            __syncthreads();
        }
    }
}

extern "C" void kernel_launch(void* const* d_in, const int* in_sizes, int n_in,
                              void* d_out, int out_size, void* d_ws, size_t ws_size,
                              hipStream_t stream) {
    const float* dz   = (const float*)d_in[0];
    const float* F0   = (const float*)d_in[1];
    const float* alph = (const float*)d_in[2];
    const float* rhos = (const float*)d_in[3];
    const float* nus  = (const float*)d_in[4];
    const float* tau  = (const float*)d_in[5];
    const float* L    = (const float*)d_in[6];
    const float* Lam  = (const float*)d_in[7];
    float* ws = (float*)d_ws;
    float* out = (float*)d_out;

    int n_paths = in_sizes[0] / (NS * 4);

    const_kernel<<<1, 64, 0, stream>>>(F0, alph, rhos, nus, tau, L, Lam, ws);
    path_kernel<<<n_paths / 2, 256, 0, stream>>>(dz, ws, out);
}

// Round 8
// 272.333 us; speedup vs baseline: 1.0409x; 1.0057x over previous
//
#include <hip/hip_runtime.h>
#include <math.h>

#define NS 512
#define NF 40
#define ROWS_OUT 513
#define DTC (1.0f / 512.0f)
#define PLANE 520   // floats per component plane (512 + 8 pad)

// ws layout (floats):
//   [0..511]      w[m]            (device-computed, fp64)
//   [512..1023]   cumw2[t]        (device-computed, fp64 prefix)
//   [1024..1343]  per-forward constants, 8 per n:
//       0..2: cC = vol_scale*L[n]   3: q = nu*rho/vol_scale
//       4: cA3 = nu*sqrt(1-rho^2)   5: ca = 0.5*nu^2*DT
//       6: cm0 = mu0*DT             7: F0[n]

__global__ __launch_bounds__(64) void const_kernel(
    const float* __restrict__ F0, const float* __restrict__ alphas,
    const float* __restrict__ rhos, const float* __restrict__ nus,
    const float* __restrict__ tau, const float* __restrict__ L,
    const float* __restrict__ Lam, float* __restrict__ ws)
{
    __shared__ double wd[NS];
    __shared__ float omega0[NF];
    __shared__ float vs_s[NF];
    int n = threadIdx.x;

    // Fractional-kernel weights in fp64 on device (no inputs needed).
    {
        const double g06 = 1.4891922488128171;      // Gamma(0.6)
        const double dta = pow(512.0, 0.4);         // DT^ALPHA
        #pragma unroll
        for (int k = 0; k < 8; ++k) {
            int m = n * 8 + k;
            double wv = (pow((double)m + 1.0, 0.6) - pow((double)m, 0.6)) * (1.0 / 0.6) * dta / g06;
            wd[m] = wv;
            ws[m] = (float)wv;
        }
    }
    if (n < NF) {
        float f0 = F0[n];
        float vs = alphas[n] * sqrtf(fabsf(f0 + 0.02f));
        vs_s[n] = vs;
        omega0[n] = tau[n] * vs / (1.0f + tau[n] * f0);
    }
    __syncthreads();
    if (n == 0) {
        // serial fp64 prefix: same accumulation order as the original host loop
        double acc = 0.0;
        for (int m = 0; m < NS; ++m) { acc += wd[m] * wd[m]; ws[NS + m] = (float)acc; }
    }
    if (n < NF) {
        float s = 0.0f;
        for (int j = 0; j < NF; ++j) s += Lam[n * NF + j] * omega0[j];
        float vs = vs_s[n];
        float mu0 = -vs * s;
        float rho = rhos[n], nu = nus[n];
        float* c = ws + 1024 + n * 8;
        c[0] = vs * L[n * 3 + 0];
        c[1] = vs * L[n * 3 + 1];
        c[2] = vs * L[n * 3 + 2];
        c[3] = nu * rho / fmaxf(vs, 1e-30f);
        c[4] = nu * sqrtf(fmaxf(1.0f - rho * rho, 0.0f));
        c[5] = 0.5f * nu * nu * DTC;
        c[6] = mu0 * DTC;
        c[7] = F0[n];
    }
}

// ---- wave64 inclusive scan via DPP (pure VALU) ----
template<int CTRL, int RM>
__device__ __forceinline__ float dpp_add(float v) {
    int t = __builtin_amdgcn_update_dpp(0, __float_as_int(v), CTRL, RM, 0xf, true);
    return v + __int_as_float(t);
}
__device__ __forceinline__ float wave_iscan(float v) {
    v = dpp_add<0x111, 0xf>(v);   // row_shr:1
    v = dpp_add<0x112, 0xf>(v);   // row_shr:2
    v = dpp_add<0x114, 0xf>(v);   // row_shr:4
    v = dpp_add<0x118, 0xf>(v);   // row_shr:8
    v = dpp_add<0x142, 0xa>(v);   // row_bcast:15 -> rows 1,3
    v = dpp_add<0x143, 0xc>(v);   // row_bcast:31 -> rows 2,3
    return v;
}

__device__ __forceinline__ void fma4(float4& acc, float c, const float4& v) {
    acc.x = fmaf(c, v.x, acc.x);
    acc.y = fmaf(c, v.y, acc.y);
    acc.z = fmaf(c, v.z, acc.z);
    acc.w = fmaf(c, v.w, acc.w);
}

// 256 threads = 4 waves; 2 paths per block.
__global__ __launch_bounds__(256, 4) void path_kernel(
    const float* __restrict__ dz, const float* __restrict__ ws,
    float* __restrict__ out)
{
    __shared__ float planes[2 * 4 * PLANE]; // 16640 B: fbm4, component-major
    __shared__ float wp[768];               // 3072 B: wp[j] = (j<256 ? 0 : w[j-256])
    __shared__ float cw2[NS];               // 2048 B
    __shared__ float chunk[64 * 41];        // 10496 B  (total 32256 B)

    int tid = threadIdx.x;
    int lane = tid & 63;
    int wv = __builtin_amdgcn_readfirstlane(tid >> 6);
    int pA = blockIdx.x * 2, pB = pA + 1;
    const float4* dzgA = (const float4*)dz + (size_t)pA * NS;
    const float4* dzgB = (const float4*)dz + (size_t)pB * NS;

    for (int i = tid; i < 768; i += 256) wp[i] = (i < 256) ? 0.0f : ws[i - 256];
    for (int i = tid; i < NS; i += 256) cw2[i] = ws[NS + i];
    __syncthreads();

    // ---- Phase B: fbm4[t] = sum_s w[t-s]*dz[s]; all 4 waves (R0 form).
    // wave = {pathA-lo, pathA-hi, pathB-lo, pathB-hi}; 4 consecutive t/thread.
    {
        int path = wv >> 1;
        int half = wv & 1;
        int i = half * 64 + lane;           // quad index: t = 4i..4i+3
        int gmax = half ? 128 : 64;         // triangular skip at wave granularity
        const float4* dzg = path ? dzgB : dzgA;
        float* pf = planes + path * 4 * PLANE;
        const float4* wp4 = (const float4*)wp;
        float4 a0 = make_float4(0.f, 0.f, 0.f, 0.f);
        float4 a1 = a0, a2 = a0, a3 = a0;
        #pragma unroll 2
        for (int g = 0; g < gmax; ++g) {
            float4 d0 = dzg[4 * g + 0];     // wave-uniform address
            float4 d1 = dzg[4 * g + 1];
            float4 d2 = dzg[4 * g + 2];
            float4 d3 = dzg[4 * g + 3];
            float4 lo = wp4[63 + i - g];    // w[t0-s0-4 .. t0-s0-1]
            float4 hi = wp4[64 + i - g];    // w[t0-s0 .. t0-s0+3]
            fma4(a0, hi.x, d0); fma4(a1, hi.y, d0); fma4(a2, hi.z, d0); fma4(a3, hi.w, d0);
            fma4(a0, lo.w, d1); fma4(a1, hi.x, d1); fma4(a2, hi.y, d1); fma4(a3, hi.z, d1);
            fma4(a0, lo.z, d2); fma4(a1, lo.w, d2); fma4(a2, hi.x, d2); fma4(a3, hi.y, d2);
            fma4(a0, lo.y, d3); fma4(a1, lo.z, d3); fma4(a2, lo.w, d3); fma4(a3, hi.x, d3);
        }
        // component-major planes: lane-stride-16B b128 writes, conflict-free
        ((float4*)(pf + 0 * PLANE))[i] = make_float4(a0.x, a1.x, a2.x, a3.x);
        ((float4*)(pf + 1 * PLANE))[i] = make_float4(a0.y, a1.y, a2.y, a3.y);
        ((float4*)(pf + 2 * PLANE))[i] = make_float4(a0.z, a1.z, a2.z, a3.z);
        ((float4*)(pf + 3 * PLANE))[i] = make_float4(a0.w, a1.w, a2.w, a3.w);
    }

    float carryA[10], carryB[10];
    #pragma unroll
    for (int j = 0; j < 10; ++j) { carryA[j] = 0.0f; carryB[j] = 0.0f; }

    float* outA = out + (size_t)pA * (ROWS_OUT * NF);
    float* outB = out + (size_t)pB * (ROWS_OUT * NF);
    if (tid < NF) outA[tid] = ws[1024 + tid * 8 + 7];               // row 0 = F0
    if (tid >= 64 && tid < 64 + NF) outB[tid - 64] = ws[1024 + (tid - 64) * 8 + 7];

    __syncthreads();

    // ---- Phase C/D: per chunk of 64 t (lane = t): dF, DPP scan, transpose, store.
    // Store phase is register-staged: barrier -> ds_read transposed values to
    // VGPRs -> barrier (chunk now reusable) -> issue HBM stores with NO barrier
    // after. The stores retire under the next j-loop's compute, so the next
    // __syncthreads' implicit vmcnt(0) drain is nearly free (vs draining 10
    // just-issued nontemporal stores synchronously, 16x per block).
    for (int cix = 0; cix < 8; ++cix) {
        int t = cix * 64 + lane;
        float cw = cw2[t];
        #pragma unroll
        for (int path = 0; path < 2; ++path) {
            const float* pf = planes + path * 4 * PLANE;
            float fx = pf[t], fy = pf[PLANE + t], fz = pf[2 * PLANE + t], fw = pf[3 * PLANE + t];
            float4 d = path ? dzgB[t] : dzgA[t];
            float* carry = path ? carryB : carryA;
            #pragma unroll
            for (int j = 0; j < 10; ++j) {
                int n = wv * 10 + j;                 // wave-uniform -> scalar loads
                const float* c = ws + 1024 + n * 8;
                float cC0 = c[0], cC1 = c[1], cC2 = c[2], q = c[3];
                float cA3 = c[4], ca = c[5], cm0 = c[6], f0 = c[7];
                float dotf = fx * cC0 + fy * cC1 + fz * cC2;
                float arg = fmaf(q, dotf, fmaf(cA3, fw, -ca * cw));
                float uv = __expf(arg);
                float dotc = d.x * cC0 + d.y * cC1 + d.z * cC2;
                float dF = uv * fmaf(cm0, uv, dotc);
                float v = wave_iscan(dF) + carry[j];
                carry[j] = __int_as_float(__builtin_amdgcn_readlane(__float_as_int(v), 63));
                chunk[lane * 41 + n] = v + f0;
            }
            __syncthreads();                         // stores from prev iter long-issued: cheap drain
            float vals[10];
            #pragma unroll
            for (int k = 0; k < 10; ++k) {
                int f = tid + k * 256;               // 2560 = 64 rows x 40 fwd, contiguous
                vals[k] = chunk[f + f / 40];         // LDS -> VGPR
            }
            __syncthreads();                         // chunk free; vmcnt already drained: cheap
            float* o = (path ? outB : outA) + NF + cix * (64 * NF);
            #pragma unroll
            for (int k = 0; k < 10; ++k) {
                int f = tid + k * 256;
                __builtin_nontemporal_store(vals[k], o + f);   // no barrier after
            }
        }
    }
}

extern "C" void kernel_launch(void* const* d_in, const int* in_sizes, int n_in,
                              void* d_out, int out_size, void* d_ws, size_t ws_size,
                              hipStream_t stream) {
    const float* dz   = (const float*)d_in[0];
    const float* F0   = (const float*)d_in[1];
    const float* alph = (const float*)d_in[2];
    const float* rhos = (const float*)d_in[3];
    const float* nus  = (const float*)d_in[4];
    const float* tau  = (const float*)d_in[5];
    const float* L    = (const float*)d_in[6];
    const float* Lam  = (const float*)d_in[7];
    float* ws = (float*)d_ws;
    float* out = (float*)d_out;

    int n_paths = in_sizes[0] / (NS * 4);

    const_kernel<<<1, 64, 0, stream>>>(F0, alph, rhos, nus, tau, L, Lam, ws);
    path_kernel<<<n_paths / 2, 256, 0, stream>>>(dz, ws, out);
}

// Round 9
// 256.202 us; speedup vs baseline: 1.1064x; 1.0630x over previous
//
#include <hip/hip_runtime.h>
#include <math.h>

#define NS 512
#define NF 40
#define ROWS_OUT 513
#define DTC (1.0f / 512.0f)
#define PLANE 512   // floats per component plane (stride-1 scalar reads: no pad needed)

// ws layout (floats):
//   [0..511]      w[m]            (device-computed, fp64)
//   [512..1023]   cumw2[t]        (device-computed, fp64 prefix)
//   [1024..1343]  per-forward constants, 8 per n:
//       0..2: cC = vol_scale*L[n]   3: q = nu*rho/vol_scale
//       4: cA3 = nu*sqrt(1-rho^2)   5: ca = 0.5*nu^2*DT
//       6: cm0 = mu0*DT             7: F0[n]

__global__ __launch_bounds__(64) void const_kernel(
    const float* __restrict__ F0, const float* __restrict__ alphas,
    const float* __restrict__ rhos, const float* __restrict__ nus,
    const float* __restrict__ tau, const float* __restrict__ L,
    const float* __restrict__ Lam, float* __restrict__ ws)
{
    __shared__ double wd[NS];
    __shared__ float omega0[NF];
    __shared__ float vs_s[NF];
    int n = threadIdx.x;

    // Fractional-kernel weights in fp64 on device (no inputs needed).
    {
        const double g06 = 1.4891922488128171;      // Gamma(0.6)
        const double dta = pow(512.0, 0.4);         // DT^ALPHA
        #pragma unroll
        for (int k = 0; k < 8; ++k) {
            int m = n * 8 + k;
            double wv = (pow((double)m + 1.0, 0.6) - pow((double)m, 0.6)) * (1.0 / 0.6) * dta / g06;
            wd[m] = wv;
            ws[m] = (float)wv;
        }
    }
    if (n < NF) {
        float f0 = F0[n];
        float vs = alphas[n] * sqrtf(fabsf(f0 + 0.02f));
        vs_s[n] = vs;
        omega0[n] = tau[n] * vs / (1.0f + tau[n] * f0);
    }
    __syncthreads();
    if (n == 0) {
        // serial fp64 prefix: same accumulation order as the original host loop
        double acc = 0.0;
        for (int m = 0; m < NS; ++m) { acc += wd[m] * wd[m]; ws[NS + m] = (float)acc; }
    }
    if (n < NF) {
        float s = 0.0f;
        for (int j = 0; j < NF; ++j) s += Lam[n * NF + j] * omega0[j];
        float vs = vs_s[n];
        float mu0 = -vs * s;
        float rho = rhos[n], nu = nus[n];
        float* c = ws + 1024 + n * 8;
        c[0] = vs * L[n * 3 + 0];
        c[1] = vs * L[n * 3 + 1];
        c[2] = vs * L[n * 3 + 2];
        c[3] = nu * rho / fmaxf(vs, 1e-30f);
        c[4] = nu * sqrtf(fmaxf(1.0f - rho * rho, 0.0f));
        c[5] = 0.5f * nu * nu * DTC;
        c[6] = mu0 * DTC;
        c[7] = F0[n];
    }
}

// ---- wave64 inclusive scan via DPP (pure VALU) ----
template<int CTRL, int RM>
__device__ __forceinline__ float dpp_add(float v) {
    int t = __builtin_amdgcn_update_dpp(0, __float_as_int(v), CTRL, RM, 0xf, true);
    return v + __int_as_float(t);
}
__device__ __forceinline__ float wave_iscan(float v) {
    v = dpp_add<0x111, 0xf>(v);   // row_shr:1
    v = dpp_add<0x112, 0xf>(v);   // row_shr:2
    v = dpp_add<0x114, 0xf>(v);   // row_shr:4
    v = dpp_add<0x118, 0xf>(v);   // row_shr:8
    v = dpp_add<0x142, 0xa>(v);   // row_bcast:15 -> rows 1,3
    v = dpp_add<0x143, 0xc>(v);   // row_bcast:31 -> rows 2,3
    return v;
}

__device__ __forceinline__ void fma4(float4& acc, float c, const float4& v) {
    acc.x = fmaf(c, v.x, acc.x);
    acc.y = fmaf(c, v.y, acc.y);
    acc.z = fmaf(c, v.z, acc.z);
    acc.w = fmaf(c, v.w, acc.w);
}

// 256 threads = 4 waves; ONE path per block; 2048 blocks = 8 blocks/CU
// (LDS 18688 B), 32 waves/CU — double the previous occupancy.
__global__ __launch_bounds__(256, 8) void path_kernel(
    const float* __restrict__ dz, const float* __restrict__ ws,
    float* __restrict__ out)
{
    __shared__ float planes[4 * PLANE];  //  8192 B: fbm4, component-major
    __shared__ float ustage[64 * 41];    // 10496 B: wp (phase B) / chunk (phase C/D)

    int tid = threadIdx.x;
    int lane = tid & 63;
    int wv = __builtin_amdgcn_readfirstlane(tid >> 6);
    int p = blockIdx.x;
    const float4* dzg = (const float4*)dz + (size_t)p * NS;

    float* wp = ustage;                  // wp[j] = (j<256 ? 0 : w[j-256]), 768 floats
    for (int i = tid; i < 768; i += 256) wp[i] = (i < 256) ? 0.0f : ws[i - 256];
    __syncthreads();

    // ---- Phase B: fbm4[t] = sum_s w[t-s]*dz[s]; 4 waves on one path.
    // role (rotated by blockIdx so each SIMD's resident waves mix trip counts):
    //   half=role>>1 picks quads [0,64) vs [64,128); seg=role&1 picks g-segment.
    //   seg1 ("writer", trips 32/64) stores its partial to planes; barrier;
    //   seg0 ("adder", trips 32/64) read-modify-adds its partial. Each float has
    //   exactly one writer and one adder lane -> race-free.
    {
        int role = (wv + p) & 3;
        int half = role >> 1;
        int seg  = role & 1;
        int i = half * 64 + lane;           // quad index: t = 4i..4i+3
        int span = half ? 64 : 32;
        int g0 = seg * span, g1 = g0 + span;
        const float4* wp4 = (const float4*)wp;
        float4 a0 = make_float4(0.f, 0.f, 0.f, 0.f);
        float4 a1 = a0, a2 = a0, a3 = a0;
        #pragma unroll 2
        for (int g = g0; g < g1; ++g) {
            float4 d0 = dzg[4 * g + 0];     // wave-uniform address
            float4 d1 = dzg[4 * g + 1];
            float4 d2 = dzg[4 * g + 2];
            float4 d3 = dzg[4 * g + 3];
            float4 lo = wp4[63 + i - g];    // w[t0-s0-4 .. t0-s0-1] (0 for s>t)
            float4 hi = wp4[64 + i - g];    // w[t0-s0 .. t0-s0+3]
            fma4(a0, hi.x, d0); fma4(a1, hi.y, d0); fma4(a2, hi.z, d0); fma4(a3, hi.w, d0);
            fma4(a0, lo.w, d1); fma4(a1, hi.x, d1); fma4(a2, hi.y, d1); fma4(a3, hi.z, d1);
            fma4(a0, lo.z, d2); fma4(a1, lo.w, d2); fma4(a2, hi.x, d2); fma4(a3, hi.y, d2);
            fma4(a0, lo.y, d3); fma4(a1, lo.z, d3); fma4(a2, lo.w, d3); fma4(a3, hi.x, d3);
        }
        if (seg == 1) {                     // writer: partial -> planes
            ((float4*)(planes + 0 * PLANE))[i] = make_float4(a0.x, a1.x, a2.x, a3.x);
            ((float4*)(planes + 1 * PLANE))[i] = make_float4(a0.y, a1.y, a2.y, a3.y);
            ((float4*)(planes + 2 * PLANE))[i] = make_float4(a0.z, a1.z, a2.z, a3.z);
            ((float4*)(planes + 3 * PLANE))[i] = make_float4(a0.w, a1.w, a2.w, a3.w);
        }
        __syncthreads();
        if (seg == 0) {                     // adder: RMW its partial into planes
            float4* q0 = &((float4*)(planes + 0 * PLANE))[i];
            float4* q1 = &((float4*)(planes + 1 * PLANE))[i];
            float4* q2 = &((float4*)(planes + 2 * PLANE))[i];
            float4* q3 = &((float4*)(planes + 3 * PLANE))[i];
            float4 c0 = *q0, c1 = *q1, c2 = *q2, c3 = *q3;
            c0.x += a0.x; c0.y += a1.x; c0.z += a2.x; c0.w += a3.x;
            c1.x += a0.y; c1.y += a1.y; c1.z += a2.y; c1.w += a3.y;
            c2.x += a0.z; c2.y += a1.z; c2.z += a2.z; c2.w += a3.z;
            c3.x += a0.w; c3.y += a1.w; c3.z += a2.w; c3.w += a3.w;
            *q0 = c0; *q1 = c1; *q2 = c2; *q3 = c3;
        }
        __syncthreads();
    }

    float carry[10];
    #pragma unroll
    for (int j = 0; j < 10; ++j) carry[j] = 0.0f;

    float* outP = out + (size_t)p * (ROWS_OUT * NF);
    if (tid < NF) outP[tid] = ws[1024 + tid * 8 + 7];               // row 0 = F0

    // ---- Phase C/D: per chunk of 64 t (lane = t): dF, DPP scan, transpose, store.
    float* chunk = ustage;                  // reuses wp's LDS (wp dead after phase B)
    const float* cwg = ws + NS;             // cumw2 from global: 2 KB, L2-hot
    for (int cix = 0; cix < 8; ++cix) {
        int t = cix * 64 + lane;
        float cw = cwg[t];
        float fx = planes[t], fy = planes[PLANE + t];
        float fz = planes[2 * PLANE + t], fw = planes[3 * PLANE + t];
        float4 d = dzg[t];
        #pragma unroll
        for (int j = 0; j < 10; ++j) {
            int n = wv * 10 + j;                 // wave-uniform -> scalar loads
            const float* c = ws + 1024 + n * 8;
            float cC0 = c[0], cC1 = c[1], cC2 = c[2], q = c[3];
            float cA3 = c[4], ca = c[5], cm0 = c[6], f0 = c[7];
            float dotf = fx * cC0 + fy * cC1 + fz * cC2;
            float arg = fmaf(q, dotf, fmaf(cA3, fw, -ca * cw));
            float uv = __expf(arg);
            float dotc = d.x * cC0 + d.y * cC1 + d.z * cC2;
            float dF = uv * fmaf(cm0, uv, dotc);
            float v = wave_iscan(dF) + carry[j];
            carry[j] = __int_as_float(__builtin_amdgcn_readlane(__float_as_int(v), 63));
            chunk[lane * 41 + n] = v + f0;
        }
        __syncthreads();
        float* o = outP + NF + cix * (64 * NF);
        #pragma unroll
        for (int k = 0; k < 10; ++k) {
            int f = tid + k * 256;               // 2560 = 64 rows x 40 fwd, contiguous
            __builtin_nontemporal_store(chunk[f + f / 40], o + f);
        }
        __syncthreads();
    }
}

extern "C" void kernel_launch(void* const* d_in, const int* in_sizes, int n_in,
                              void* d_out, int out_size, void* d_ws, size_t ws_size,
                              hipStream_t stream) {
    const float* dz   = (const float*)d_in[0];
    const float* F0   = (const float*)d_in[1];
    const float* alph = (const float*)d_in[2];
    const float* rhos = (const float*)d_in[3];
    const float* nus  = (const float*)d_in[4];
    const float* tau  = (const float*)d_in[5];
    const float* L    = (const float*)d_in[6];
    const float* Lam  = (const float*)d_in[7];
    float* ws = (float*)d_ws;
    float* out = (float*)d_out;

    int n_paths = in_sizes[0] / (NS * 4);

    const_kernel<<<1, 64, 0, stream>>>(F0, alph, rhos, nus, tau, L, Lam, ws);
    path_kernel<<<n_paths, 256, 0, stream>>>(dz, ws, out);
}